// Round 14
// baseline (663.139 us; speedup 1.0000x reference)
//
#include <hip/hip_runtime.h>

// MotherNet forward — R14: R12 baseline + AMPLIFICATION PROBE.
// Each idempotent per-layer kernel (qkv, flash, proj, ff1, ff2) is launched
// TWICE (second launch reads identical inputs, writes identical outputs).
// dur - 428us = marginal cost of those 20 launches. Output is bit-identical.

#define BATCH  2
#define FDIM   100
#define EDIM   512
#define NHEADS 8
#define HD     64
#define NHID   1024
#define NLAYER 4
#define HDIM   128
#define NOUTD  10
#define DECD   2048
#define SEPP   1024
#define TOTALW 30730
#define NTOK   2048

typedef unsigned short u16;
typedef __attribute__((ext_vector_type(8))) short bf16x8;
typedef __attribute__((ext_vector_type(4))) float f32x4;

__device__ __forceinline__ float nanfix(float v) {
    if (isnan(v)) return 0.f;
    if (isinf(v)) return v > 0.f ? 3.4028234663852886e38f : -3.4028234663852886e38f;
    return v;
}
__device__ __forceinline__ u16 f2bf(float f) {   // RTNE, finite inputs
    unsigned u = __float_as_uint(f);
    u += 0x7fffu + ((u >> 16) & 1u);
    return (u16)(u >> 16);
}
__device__ __forceinline__ float bf2f(u16 h) {
    return __uint_as_float(((unsigned)h) << 16);
}
__device__ __forceinline__ bf16x8 scale8(bf16x8 a, float s) {
    bf16x8 r;
    #pragma unroll
    for (int i = 0; i < 8; i++) {
        float v = bf2f((u16)a[i]) * s;
        r[i] = (short)f2bf(v);
    }
    return r;
}

#define GLOAD16(gsrc, ldst) \
    __builtin_amdgcn_global_load_lds( \
        (const __attribute__((address_space(1))) void*)(gsrc), \
        (__attribute__((address_space(3))) void*)(ldst), 16, 0, 0)

// ---------------------------------------------------------------------------
// gemm2 (R10 3-buffer counted-vmcnt, 64^2) with optional fused V-transpose
// epilogue (R11) — identical to R12's gemm2.
// ---------------------------------------------------------------------------
__global__ __launch_bounds__(256) void gemm2(
    const u16* __restrict__ A, int lda,
    const u16* __restrict__ B, int ldb,
    void* __restrict__ Cv, int ldc, int cbf,
    int K, long long zCstride, float alpha,
    const float* __restrict__ bias, int act,
    u16* __restrict__ vtout)
{
    __shared__ __align__(16) u16 lds[3][8192];

    int tid = threadIdx.x;
    int lane = tid & 63, w = tid >> 6;
    int wr = w >> 1, wc = w & 1;
    int mBase = blockIdx.y * 64, nBase = blockIdx.x * 64;
    int r16 = lane & 15, kg = lane >> 4;
    long long zk = (long long)blockIdx.z * K;
    long long offC = (long long)blockIdx.z * zCstride;

    int c0 = w * 64 + lane;
    int c1 = 256 + w * 64 + lane;
    int r0 = c0 >> 3, r1 = c1 >> 3;
    int e0 = ((((c0 & 7) * 16) ^ ((r0 & 7) << 4)) >> 1);
    int e1 = ((((c1 & 7) * 16) ^ ((r1 & 7) << 4)) >> 1);
    const u16* sA0 = A + (long long)(mBase + r0) * lda + e0 + zk;
    const u16* sA1 = A + (long long)(mBase + r1) * lda + e1 + zk;
    const u16* sB0 = B + (long long)(nBase + r0) * ldb + e0 + zk;
    const u16* sB1 = B + (long long)(nBase + r1) * ldb + e1 + zk;
    int dA0 = w * 512, dA1 = 2048 + w * 512;
    int dB0 = 4096 + w * 512, dB1 = 6144 + w * 512;

    int ra0 = wr * 32 + r16,      ra1 = wr * 32 + 16 + r16;
    int rb0 = wc * 32 + r16,      rb1 = wc * 32 + 16 + r16;
    int cb0 = kg * 16;
    int cb1 = 64 + kg * 16;
    int oa00 = (ra0 * 128 + (cb0 ^ ((ra0 & 7) << 4))) >> 1;
    int oa01 = (ra0 * 128 + (cb1 ^ ((ra0 & 7) << 4))) >> 1;
    int oa10 = (ra1 * 128 + (cb0 ^ ((ra1 & 7) << 4))) >> 1;
    int oa11 = (ra1 * 128 + (cb1 ^ ((ra1 & 7) << 4))) >> 1;
    int ob00 = 4096 + ((rb0 * 128 + (cb0 ^ ((rb0 & 7) << 4))) >> 1);
    int ob01 = 4096 + ((rb0 * 128 + (cb1 ^ ((rb0 & 7) << 4))) >> 1);
    int ob10 = 4096 + ((rb1 * 128 + (cb0 ^ ((rb1 & 7) << 4))) >> 1);
    int ob11 = 4096 + ((rb1 * 128 + (cb1 ^ ((rb1 & 7) << 4))) >> 1);

    f32x4 acc00 = {0.f, 0.f, 0.f, 0.f};
    f32x4 acc01 = acc00, acc10 = acc00, acc11 = acc00;

    int nt = K >> 6;

#define STAGE2(t, bi) { int ko_ = (t) << 6; \
    GLOAD16(sA0 + ko_, &lds[bi][dA0]); \
    GLOAD16(sA1 + ko_, &lds[bi][dA1]); \
    GLOAD16(sB0 + ko_, &lds[bi][dB0]); \
    GLOAD16(sB1 + ko_, &lds[bi][dB1]); }

    STAGE2(0, 0);
    STAGE2(1, 1);

    int cur = 0;
    for (int t = 0; t < nt; t++) {
        if (t == nt - 1) {
            asm volatile("s_waitcnt vmcnt(0)" ::: "memory");
        } else {
            asm volatile("s_waitcnt vmcnt(4)" ::: "memory");
        }
        __builtin_amdgcn_s_barrier();
        if (t + 2 < nt) {
            int tgt = cur - 1; if (tgt < 0) tgt += 3;
            STAGE2(t + 2, tgt);
        }
        const u16* L = &lds[cur][0];
        bf16x8 a0 = *(const bf16x8*)(L + oa00);
        bf16x8 a1 = *(const bf16x8*)(L + oa10);
        bf16x8 b0 = *(const bf16x8*)(L + ob00);
        bf16x8 b1 = *(const bf16x8*)(L + ob10);
        acc00 = __builtin_amdgcn_mfma_f32_16x16x32_bf16(a0, b0, acc00, 0, 0, 0);
        acc01 = __builtin_amdgcn_mfma_f32_16x16x32_bf16(a0, b1, acc01, 0, 0, 0);
        acc10 = __builtin_amdgcn_mfma_f32_16x16x32_bf16(a1, b0, acc10, 0, 0, 0);
        acc11 = __builtin_amdgcn_mfma_f32_16x16x32_bf16(a1, b1, acc11, 0, 0, 0);
        a0 = *(const bf16x8*)(L + oa01);
        a1 = *(const bf16x8*)(L + oa11);
        b0 = *(const bf16x8*)(L + ob01);
        b1 = *(const bf16x8*)(L + ob11);
        acc00 = __builtin_amdgcn_mfma_f32_16x16x32_bf16(a0, b0, acc00, 0, 0, 0);
        acc01 = __builtin_amdgcn_mfma_f32_16x16x32_bf16(a0, b1, acc01, 0, 0, 0);
        acc10 = __builtin_amdgcn_mfma_f32_16x16x32_bf16(a1, b0, acc10, 0, 0, 0);
        acc11 = __builtin_amdgcn_mfma_f32_16x16x32_bf16(a1, b1, acc11, 0, 0, 0);
        cur++; if (cur == 3) cur = 0;
    }
#undef STAGE2

    if (vtout && nBase >= 1024) {
        u16* T = &lds[0][0];                 // [m_local][d_local] 64x64 u16
        __syncthreads();
        #pragma unroll
        for (int i = 0; i < 2; i++) {
            #pragma unroll
            for (int j = 0; j < 2; j++) {
                f32x4 v = (i == 0) ? (j == 0 ? acc00 : acc01) : (j == 0 ? acc10 : acc11);
                int dl = wc * 32 + j * 16 + r16;
                float bv = bias ? bias[nBase + dl] : 0.f;
                #pragma unroll
                for (int r = 0; r < 4; r++) {
                    int ml = wr * 32 + i * 16 + kg * 4 + r;
                    T[ml * 64 + dl] = f2bf(v[r] * alpha + bv);
                }
            }
        }
        __syncthreads();
        int d = tid & 63, cbv = (tid >> 6) & 1, half = tid >> 7;
        int hh = (nBase - 1024) >> 6;
        long long orow = ((long long)(cbv * 8 + hh) * 64 + d) * 1024 + (mBase >> 1) + half * 16;
        bf16x8 v0, v1;
        #pragma unroll
        for (int k = 0; k < 8; k++) {
            v0[k] = (short)T[((half * 16 + k) * 2 + cbv) * 64 + d];
            v1[k] = (short)T[((half * 16 + 8 + k) * 2 + cbv) * 64 + d];
        }
        *(bf16x8*)(vtout + orow) = v0;
        *(bf16x8*)(vtout + orow + 8) = v1;
        return;
    }

    #pragma unroll
    for (int i = 0; i < 2; i++) {
        #pragma unroll
        for (int j = 0; j < 2; j++) {
            f32x4 v = (i == 0) ? (j == 0 ? acc00 : acc01) : (j == 0 ? acc10 : acc11);
            int col = nBase + wc * 32 + j * 16 + r16;
            float bv = bias ? bias[col] : 0.f;
            long long base = offC + (long long)(mBase + wr * 32 + i * 16 + kg * 4) * ldc + col;
            #pragma unroll
            for (int r = 0; r < 4; r++) {
                float c = v[r] * alpha + bv;
                if (act == 2) {
                    float u = 0.7978845608028654f * (c + 0.044715f * c * c * c);
                    c = 0.5f * c * (1.f + tanhf(u));
                }
                if (cbf) ((u16*)Cv)[base + (long long)r * ldc] = f2bf(c);
                else     ((float*)Cv)[base + (long long)r * ldc] = c;
            }
        }
    }
}

// ---------------------------------------------------------------------------
// Flash v4 (R12): defer-max, kv-split x4, 1024 threads.
// ---------------------------------------------------------------------------
__global__ __launch_bounds__(1024) void flash_attn(
    const u16* __restrict__ qkvb, const u16* __restrict__ vtm,
    u16* __restrict__ attnb)
{
    int qt = blockIdx.x;
    int bh = blockIdx.y;
    int cb = bh >> 3, hh = bh & 7;
    int tid = threadIdx.x;
    int w = tid >> 6, lane = tid & 63;
    int p = w & 3, qf = w >> 2;
    int r16 = lane & 15, kg = lane >> 4;

    __shared__ __align__(16) u16 plds[16][2048];
    u16* pl = &plds[w][0];

    int qrow = qt * 64 + p * 16 + r16;
    const u16* qp = qkvb + ((long long)qrow * 2 + cb) * 1536 + hh * 64 + kg * 8;
    bf16x8 qf0 = scale8(*(const bf16x8*)(qp), 0.125f);
    bf16x8 qf1 = scale8(*(const bf16x8*)(qp + 32), 0.125f);

    const u16* kbase = qkvb + (long long)cb * 1536 + 512 + hh * 64;
    const u16* vbase = vtm + ((long long)bh * 64) * 1024;

    f32x4 l = {0.f, 0.f, 0.f, 0.f};
    f32x4 o[4] = {};

    int rb0 = (((r16 * 64 + kg * 8) * 2) ^ ((r16 & 7) << 4)) >> 1;
    int rb1 = (((r16 * 64 + 32 + kg * 8) * 2) ^ ((r16 & 7) << 4)) >> 1;

    for (int kt = qf * 4; kt < qf * 4 + 4; kt++) {
        f32x4 s[4];
        #pragma unroll
        for (int nb = 0; nb < 4; nb++) {
            int key = kt * 64 + nb * 16 + r16;
            const u16* kp = kbase + (long long)key * 3072 + kg * 8;
            bf16x8 kf0 = *(const bf16x8*)(kp);
            bf16x8 kf1 = *(const bf16x8*)(kp + 32);
            f32x4 acc = {};
            acc = __builtin_amdgcn_mfma_f32_16x16x32_bf16(qf0, kf0, acc, 0, 0, 0);
            acc = __builtin_amdgcn_mfma_f32_16x16x32_bf16(qf1, kf1, acc, 0, 0, 0);
            s[nb] = acc;
        }
        f32x4 rs = {};
        #pragma unroll
        for (int nb = 0; nb < 4; nb++)
            #pragma unroll
            for (int r = 0; r < 4; r++) {
                float pv = __expf(s[nb][r]);
                s[nb][r] = pv;
                rs[r] += pv;
            }
        #pragma unroll
        for (int off = 1; off < 16; off <<= 1) {
            #pragma unroll
            for (int r = 0; r < 4; r++) rs[r] += __shfl_xor(rs[r], off);
        }
        #pragma unroll
        for (int r = 0; r < 4; r++) l[r] += rs[r];

        #pragma unroll
        for (int nb = 0; nb < 4; nb++)
            #pragma unroll
            for (int r = 0; r < 4; r++) {
                int row = kg * 4 + r;
                int col = nb * 16 + r16;
                int byi = (((row * 64 + col) * 2) ^ ((row & 7) << 4)) >> 1;
                pl[byi] = f2bf(s[nb][r]);
            }

        bf16x8 pa0 = *(const bf16x8*)(pl + rb0);
        bf16x8 pa1 = *(const bf16x8*)(pl + rb1);
        #pragma unroll
        for (int db = 0; db < 4; db++) {
            const u16* vp = vbase + (long long)(db * 16 + r16) * 1024 + kt * 64 + kg * 8;
            bf16x8 vf0 = *(const bf16x8*)(vp);
            bf16x8 vf1 = *(const bf16x8*)(vp + 32);
            o[db] = __builtin_amdgcn_mfma_f32_16x16x32_bf16(pa0, vf0, o[db], 0, 0, 0);
            o[db] = __builtin_amdgcn_mfma_f32_16x16x32_bf16(pa1, vf1, o[db], 0, 0, 0);
        }
    }

    __syncthreads();
    float* fb = (float*)&plds[0][0];
    if (qf < 3) {
        int base = ((qf * 4 + p) * 64 + lane) * 20;
        #pragma unroll
        for (int r = 0; r < 4; r++) fb[base + r] = l[r];
        #pragma unroll
        for (int db = 0; db < 4; db++)
            #pragma unroll
            for (int r = 0; r < 4; r++) fb[base + 4 + db * 4 + r] = o[db][r];
    }
    __syncthreads();
    if (qf == 3) {
        #pragma unroll
        for (int q2 = 0; q2 < 3; q2++) {
            int base = ((q2 * 4 + p) * 64 + lane) * 20;
            #pragma unroll
            for (int r = 0; r < 4; r++) l[r] += fb[base + r];
            #pragma unroll
            for (int db = 0; db < 4; db++)
                #pragma unroll
                for (int r = 0; r < 4; r++) o[db][r] += fb[base + 4 + db * 4 + r];
        }
        f32x4 linv;
        #pragma unroll
        for (int r = 0; r < 4; r++) linv[r] = 1.f / l[r];
        #pragma unroll
        for (int db = 0; db < 4; db++)
            #pragma unroll
            for (int r = 0; r < 4; r++) {
                float val = o[db][r] * linv[r];
                int row = qt * 64 + p * 16 + kg * 4 + r;
                attnb[((long long)row * 2 + cb) * 512 + hh * 64 + db * 16 + r16] = f2bf(val);
            }
    }
}

// merged f32->bf16 convert for the 4 transformer weight tensors
__global__ __launch_bounds__(256) void cvt_all(
    const float* __restrict__ s0, const float* __restrict__ s1,
    const float* __restrict__ s2, const float* __restrict__ s3,
    u16* __restrict__ d0, u16* __restrict__ d1,
    u16* __restrict__ d2, u16* __restrict__ d3)
{
    const int n0 = 3145728, n1 = 1048576, n2 = 2097152, n3 = 2097152;
    int i = blockIdx.x * 256 + threadIdx.x;
    int st = gridDim.x * 256;
    for (; i < n0 + n1 + n2 + n3; i += st) {
        if (i < n0) d0[i] = f2bf(s0[i]);
        else if (i < n0 + n1) d1[i - n0] = f2bf(s1[i - n0]);
        else if (i < n0 + n1 + n2) d2[i - n0 - n1] = f2bf(s2[i - n0 - n1]);
        else d3[i - n0 - n1 - n2] = f2bf(s3[i - n0 - n1 - n2]);
    }
}

// Encoder, 16 tokens per block
__global__ __launch_bounds__(512) void encoder_kernel(
    const float* __restrict__ x, const float* __restrict__ y,
    const float* __restrict__ enc_w, const float* __restrict__ enc_b,
    const float* __restrict__ yenc_w, const float* __restrict__ yenc_b,
    float* __restrict__ h, u16* __restrict__ h_bf)
{
    int g = blockIdx.x;
    int tid = threadIdx.x;
    __shared__ float xs[16][FDIM];
    __shared__ float ys[16];
    for (int i = tid; i < 16 * FDIM; i += 512) {
        int tk = i / FDIM, f = i % FDIM;
        xs[tk][f] = nanfix(x[(long long)(g * 16 + tk) * FDIM + f]);
    }
    if (tid < 16) ys[tid] = y[g * 16 + tid];
    __syncthreads();
    float base = enc_b[tid] + yenc_b[tid];
    float yw = yenc_w[tid];
    const float* wr = enc_w + (long long)tid * FDIM;
    float acc[16];
    #pragma unroll
    for (int j = 0; j < 16; j++) acc[j] = 0.f;
    for (int f = 0; f < FDIM; f++) {
        float wv = wr[f];
        #pragma unroll
        for (int j = 0; j < 16; j++) acc[j] = fmaf(xs[j][f], wv, acc[j]);
    }
    #pragma unroll
    for (int j = 0; j < 16; j++) {
        float v = base + ys[j] * yw + acc[j];
        long long t = g * 16 + j;
        h[t * EDIM + tid] = v;
        h_bf[t * EDIM + tid] = f2bf(v);
    }
}

// out = LN(a + p0 + p1 + cbias)*g + be ; writes f32 + bf16. a may alias out.
__global__ __launch_bounds__(256) void add_ln3_kernel(
    const float* a, const float* __restrict__ p0, const float* __restrict__ p1,
    const float* __restrict__ cbias,
    const float* __restrict__ g, const float* __restrict__ be,
    float* out, u16* __restrict__ out_bf)
{
    int row = blockIdx.x;
    int tid = threadIdx.x;
    const float* pa = a + (long long)row * EDIM;
    const float* pr0 = p0 + (long long)row * EDIM;
    const float* pr1 = p1 + (long long)row * EDIM;
    float v0 = pa[tid] + pr0[tid] + pr1[tid] + cbias[tid];
    float v1 = pa[tid + 256] + pr0[tid + 256] + pr1[tid + 256] + cbias[tid + 256];
    float s = v0 + v1, q = v0 * v0 + v1 * v1;
    #pragma unroll
    for (int off = 32; off; off >>= 1) {
        s += __shfl_xor(s, off);
        q += __shfl_xor(q, off);
    }
    __shared__ float ss[4], sq[4];
    int w = tid >> 6, lane = tid & 63;
    if (lane == 0) { ss[w] = s; sq[w] = q; }
    __syncthreads();
    s = ss[0] + ss[1] + ss[2] + ss[3];
    q = sq[0] + sq[1] + sq[2] + sq[3];
    float mean = s * (1.f / EDIM);
    float var = q * (1.f / EDIM) - mean * mean;
    float rstd = rsqrtf(var + 1e-5f);
    float o0 = (v0 - mean) * rstd * g[tid] + be[tid];
    float o1 = (v1 - mean) * rstd * g[tid + 256] + be[tid + 256];
    float* po = out + (long long)row * EDIM;
    u16* pb = out_bf + (long long)row * EDIM;
    po[tid] = o0;        po[tid + 256] = o1;
    pb[tid] = f2bf(o0);  pb[tid + 256] = f2bf(o1);
}

// two-stage coalesced mean-pool
__global__ __launch_bounds__(1024) void pool1_kernel(
    const float* __restrict__ h, float* __restrict__ part)
{
    int j = blockIdx.x;
    int idx = threadIdx.x;
    float s = 0.f;
    #pragma unroll 8
    for (int k = 0; k < 32; k++)
        s += h[(long long)(j * 32 + k) * 1024 + idx];
    part[j * 1024 + idx] = s;
}
__global__ __launch_bounds__(1024) void pool2_kernel(
    const float* __restrict__ part, float* __restrict__ pooled)
{
    int idx = threadIdx.x;
    float s = 0.f;
    #pragma unroll 8
    for (int j = 0; j < 32; j++) s += part[j * 1024 + idx];
    pooled[idx] = s * (1.f / 1024.f);
}

__global__ __launch_bounds__(256) void wavedot2_kernel(
    const float* __restrict__ v0, const float* __restrict__ v1,
    const float* __restrict__ W, const float* __restrict__ bias,
    float* __restrict__ out0, float* __restrict__ out1,
    int R, int K, int act)
{
    int gw = (blockIdx.x * 256 + threadIdx.x) >> 6;
    int lane = threadIdx.x & 63;
    int nw = (gridDim.x * 256) >> 6;
    const float4* x0 = (const float4*)v0;
    const float4* x1 = (const float4*)v1;
    for (int r = gw; r < R; r += nw) {
        const float4* w4 = (const float4*)(W + (long long)r * K);
        float a0 = 0.f, a1 = 0.f;
        for (int i = lane; i < (K >> 2); i += 64) {
            float4 w = w4[i];
            float4 p = x0[i];
            float4 q = x1[i];
            a0 += w.x * p.x + w.y * p.y + w.z * p.z + w.w * p.w;
            a1 += w.x * q.x + w.y * q.y + w.z * q.z + w.w * q.w;
        }
        #pragma unroll
        for (int off = 32; off; off >>= 1) {
            a0 += __shfl_xor(a0, off);
            a1 += __shfl_xor(a1, off);
        }
        if (lane == 0) {
            float bb = bias[r];
            float o0 = a0 + bb, o1 = a1 + bb;
            if (act == 1) { o0 = fmaxf(o0, 0.f); o1 = fmaxf(o1, 0.f); }
            out0[r] = o0; out1[r] = o1;
        }
    }
}

// Final per-sample MLP, 8 same-parity tokens per block.
__global__ __launch_bounds__(128) void final_mlp_kernel(
    const float* __restrict__ x, const float* __restrict__ flat,
    float* __restrict__ out)
{
    int g = blockIdx.x;
    int b = g >> 7;
    int j0 = (g & 127) * 8;
    int tid = threadIdx.x;
    const float* fl = flat + (long long)b * TOTALW;
    __shared__ float xs[8][FDIM], t1s[8][HDIM], t2s[8][HDIM];
    for (int i = tid; i < 8 * FDIM; i += 128) {
        int j = i / FDIM, f = i % FDIM;
        int t = (j0 + j) * 2 + b;
        xs[j][f] = nanfix(x[(long long)(NTOK + t) * FDIM + f]);
    }
    __syncthreads();
    {
        float acc[8];
        float b1 = fl[tid];
        #pragma unroll
        for (int j = 0; j < 8; j++) acc[j] = b1;
        const float* w1 = fl + HDIM;
        for (int f = 0; f < FDIM; f++) {
            float wv = w1[f * HDIM + tid];
            #pragma unroll
            for (int j = 0; j < 8; j++) acc[j] = fmaf(xs[j][f], wv, acc[j]);
        }
        #pragma unroll
        for (int j = 0; j < 8; j++) t1s[j][tid] = fmaxf(acc[j], 0.f);
    }
    __syncthreads();
    {
        float acc[8];
        float b2 = fl[12928 + tid];
        #pragma unroll
        for (int j = 0; j < 8; j++) acc[j] = b2;
        const float* w2 = fl + 13056;
        for (int hh = 0; hh < HDIM; hh++) {
            float wv = w2[hh * HDIM + tid];
            #pragma unroll
            for (int j = 0; j < 8; j++) acc[j] = fmaf(t1s[j][hh], wv, acc[j]);
        }
        #pragma unroll
        for (int j = 0; j < 8; j++) t2s[j][tid] = fmaxf(acc[j], 0.f);
    }
    __syncthreads();
    if (tid < NOUTD) {
        float acc[8];
        float b3 = fl[29440 + tid];
        #pragma unroll
        for (int j = 0; j < 8; j++) acc[j] = b3;
        const float* w3 = fl + 29450;
        for (int hh = 0; hh < HDIM; hh++) {
            float wv = w3[hh * NOUTD + tid];
            #pragma unroll
            for (int j = 0; j < 8; j++) acc[j] = fmaf(t2s[j][hh], wv, acc[j]);
        }
        #pragma unroll
        for (int j = 0; j < 8; j++) {
            int t = (j0 + j) * 2 + b;
            out[(long long)t * NOUTD + tid] = acc[j];
        }
    }
}

// ---------------------------------------------------------------------------
extern "C" void kernel_launch(void* const* d_in, const int* in_sizes, int n_in,
                              void* d_out, int out_size, void* d_ws, size_t ws_size,
                              hipStream_t stream) {
    const float* x      = (const float*)d_in[0];
    const float* y      = (const float*)d_in[1];
    const float* enc_w  = (const float*)d_in[2];
    const float* enc_b  = (const float*)d_in[3];
    const float* yenc_w = (const float*)d_in[4];
    const float* yenc_b = (const float*)d_in[5];
    const float* qkv_w  = (const float*)d_in[6];
    const float* qkv_b  = (const float*)d_in[7];
    const float* out_w  = (const float*)d_in[8];
    const float* out_b  = (const float*)d_in[9];
    const float* ln1_g  = (const float*)d_in[10];
    const float* ln1_b  = (const float*)d_in[11];
    const float* ln2_g  = (const float*)d_in[12];
    const float* ln2_b  = (const float*)d_in[13];
    const float* ff1_w  = (const float*)d_in[14];
    const float* ff1_b  = (const float*)d_in[15];
    const float* ff2_w  = (const float*)d_in[16];
    const float* ff2_b  = (const float*)d_in[17];
    const float* dec_w1 = (const float*)d_in[18];
    const float* dec_b1 = (const float*)d_in[19];
    const float* dec_w2 = (const float*)d_in[20];
    const float* dec_b2 = (const float*)d_in[21];

    float* ws     = (float*)d_ws;
    float* h      = ws;
    u16*   h_bf   = (u16*)(h + 1048576);
    u16*   qkv_bf = h_bf + 1048576;
    u16*   vt     = qkv_bf + 3145728;
    u16*   attn_bf= vt + 1048576;
    u16*   ffb_bf = attn_bf + 1048576;
    u16*   wq     = ffb_bf + 2097152;
    u16*   wo     = wq + 3145728;
    u16*   wf1    = wo + 1048576;
    u16*   wf2    = wf1 + 2097152;
    float* big    = (float*)(wf2 + 2097152);
    float* big2   = big + 1048576;
    float* part   = big2 + 1048576;
    float* pooled = part + 32768;
    float* dbuf   = pooled + 1024;
    float* flat   = dbuf + 4096;

    cvt_all<<<4096, 256, 0, stream>>>(qkv_w, out_w, ff1_w, ff2_w, wq, wo, wf1, wf2);

    encoder_kernel<<<128, 512, 0, stream>>>(x, y, enc_w, enc_b, yenc_w, yenc_b, h, h_bf);

    const long long PSTRIDE = (long long)NTOK * EDIM;

    for (int l = 0; l < NLAYER; l++) {
        // --- AMPLIFIED x2: qkv (idempotent) ---
        for (int rep = 0; rep < 2; rep++)
            gemm2<<<dim3(24, 32, 1), 256, 0, stream>>>(
                h_bf, EDIM, wq + (size_t)l * 786432, EDIM,
                qkv_bf, 1536, 1, EDIM, 0, 1.f, qkv_b + (size_t)l * 1536, 0, vt);

        // --- AMPLIFIED x2: flash (idempotent) ---
        for (int rep = 0; rep < 2; rep++)
            flash_attn<<<dim3(16, 16), 1024, 0, stream>>>(qkv_bf, vt, attn_bf);

        // --- AMPLIFIED x2: proj partials (idempotent) ---
        for (int rep = 0; rep < 2; rep++)
            gemm2<<<dim3(8, 32, 2), 256, 0, stream>>>(
                attn_bf, EDIM, wo + (size_t)l * 262144, EDIM,
                big, EDIM, 0, 256, PSTRIDE, 1.f, nullptr, 0, nullptr);

        add_ln3_kernel<<<NTOK, 256, 0, stream>>>(h, big, big2,
            out_b + (size_t)l * EDIM,
            ln1_g + (size_t)l * EDIM, ln1_b + (size_t)l * EDIM, h, h_bf);

        // --- AMPLIFIED x2: ff1 (idempotent) ---
        for (int rep = 0; rep < 2; rep++)
            gemm2<<<dim3(16, 32, 1), 256, 0, stream>>>(
                h_bf, EDIM, wf1 + (size_t)l * 524288, EDIM,
                ffb_bf, NHID, 1, EDIM, 0, 1.f, ff1_b + (size_t)l * NHID, 2, nullptr);

        // --- AMPLIFIED x2: ff2 partials (idempotent) ---
        for (int rep = 0; rep < 2; rep++)
            gemm2<<<dim3(8, 32, 2), 256, 0, stream>>>(
                ffb_bf, NHID, wf2 + (size_t)l * 524288, NHID,
                big, EDIM, 0, 512, PSTRIDE, 1.f, nullptr, 0, nullptr);

        add_ln3_kernel<<<NTOK, 256, 0, stream>>>(h, big, big2,
            ff2_b + (size_t)l * EDIM,
            ln2_g + (size_t)l * EDIM, ln2_b + (size_t)l * EDIM, h, h_bf);
    }

    pool1_kernel<<<32, 1024, 0, stream>>>(h, part);
    pool2_kernel<<<1, 1024, 0, stream>>>(part, pooled);

    wavedot2_kernel<<<512, 256, 0, stream>>>(
        pooled, pooled + EDIM, dec_w1, dec_b1, dbuf, dbuf + DECD, DECD, EDIM, 1);

    wavedot2_kernel<<<7683, 256, 0, stream>>>(
        dbuf, dbuf + DECD, dec_w2, dec_b2, flat, flat + TOTALW, TOTALW, DECD, 0);

    final_mlp_kernel<<<256, 128, 0, stream>>>(x, flat, (float*)d_out);
}

// Round 15
// 416.114 us; speedup vs baseline: 1.5936x; 1.5936x over previous
//
#include <hip/hip_runtime.h>

// MotherNet forward — R15: R12 baseline + grid-fill fixes for encoder (256
// blocks), final_mlp (512 blocks), and float2-vectorized add_ln3.

#define BATCH  2
#define FDIM   100
#define EDIM   512
#define NHEADS 8
#define HD     64
#define NHID   1024
#define NLAYER 4
#define HDIM   128
#define NOUTD  10
#define DECD   2048
#define SEPP   1024
#define TOTALW 30730
#define NTOK   2048

typedef unsigned short u16;
typedef __attribute__((ext_vector_type(8))) short bf16x8;
typedef __attribute__((ext_vector_type(4))) float f32x4;

__device__ __forceinline__ float nanfix(float v) {
    if (isnan(v)) return 0.f;
    if (isinf(v)) return v > 0.f ? 3.4028234663852886e38f : -3.4028234663852886e38f;
    return v;
}
__device__ __forceinline__ u16 f2bf(float f) {   // RTNE, finite inputs
    unsigned u = __float_as_uint(f);
    u += 0x7fffu + ((u >> 16) & 1u);
    return (u16)(u >> 16);
}
__device__ __forceinline__ float bf2f(u16 h) {
    return __uint_as_float(((unsigned)h) << 16);
}
__device__ __forceinline__ bf16x8 scale8(bf16x8 a, float s) {
    bf16x8 r;
    #pragma unroll
    for (int i = 0; i < 8; i++) {
        float v = bf2f((u16)a[i]) * s;
        r[i] = (short)f2bf(v);
    }
    return r;
}

#define GLOAD16(gsrc, ldst) \
    __builtin_amdgcn_global_load_lds( \
        (const __attribute__((address_space(1))) void*)(gsrc), \
        (__attribute__((address_space(3))) void*)(ldst), 16, 0, 0)

// ---------------------------------------------------------------------------
// gemm2 (3-buffer counted-vmcnt, 64^2) with optional fused V-transpose.
// ---------------------------------------------------------------------------
__global__ __launch_bounds__(256) void gemm2(
    const u16* __restrict__ A, int lda,
    const u16* __restrict__ B, int ldb,
    void* __restrict__ Cv, int ldc, int cbf,
    int K, long long zCstride, float alpha,
    const float* __restrict__ bias, int act,
    u16* __restrict__ vtout)
{
    __shared__ __align__(16) u16 lds[3][8192];

    int tid = threadIdx.x;
    int lane = tid & 63, w = tid >> 6;
    int wr = w >> 1, wc = w & 1;
    int mBase = blockIdx.y * 64, nBase = blockIdx.x * 64;
    int r16 = lane & 15, kg = lane >> 4;
    long long zk = (long long)blockIdx.z * K;
    long long offC = (long long)blockIdx.z * zCstride;

    int c0 = w * 64 + lane;
    int c1 = 256 + w * 64 + lane;
    int r0 = c0 >> 3, r1 = c1 >> 3;
    int e0 = ((((c0 & 7) * 16) ^ ((r0 & 7) << 4)) >> 1);
    int e1 = ((((c1 & 7) * 16) ^ ((r1 & 7) << 4)) >> 1);
    const u16* sA0 = A + (long long)(mBase + r0) * lda + e0 + zk;
    const u16* sA1 = A + (long long)(mBase + r1) * lda + e1 + zk;
    const u16* sB0 = B + (long long)(nBase + r0) * ldb + e0 + zk;
    const u16* sB1 = B + (long long)(nBase + r1) * ldb + e1 + zk;
    int dA0 = w * 512, dA1 = 2048 + w * 512;
    int dB0 = 4096 + w * 512, dB1 = 6144 + w * 512;

    int ra0 = wr * 32 + r16,      ra1 = wr * 32 + 16 + r16;
    int rb0 = wc * 32 + r16,      rb1 = wc * 32 + 16 + r16;
    int cb0 = kg * 16;
    int cb1 = 64 + kg * 16;
    int oa00 = (ra0 * 128 + (cb0 ^ ((ra0 & 7) << 4))) >> 1;
    int oa01 = (ra0 * 128 + (cb1 ^ ((ra0 & 7) << 4))) >> 1;
    int oa10 = (ra1 * 128 + (cb0 ^ ((ra1 & 7) << 4))) >> 1;
    int oa11 = (ra1 * 128 + (cb1 ^ ((ra1 & 7) << 4))) >> 1;
    int ob00 = 4096 + ((rb0 * 128 + (cb0 ^ ((rb0 & 7) << 4))) >> 1);
    int ob01 = 4096 + ((rb0 * 128 + (cb1 ^ ((rb0 & 7) << 4))) >> 1);
    int ob10 = 4096 + ((rb1 * 128 + (cb0 ^ ((rb1 & 7) << 4))) >> 1);
    int ob11 = 4096 + ((rb1 * 128 + (cb1 ^ ((rb1 & 7) << 4))) >> 1);

    f32x4 acc00 = {0.f, 0.f, 0.f, 0.f};
    f32x4 acc01 = acc00, acc10 = acc00, acc11 = acc00;

    int nt = K >> 6;

#define STAGE2(t, bi) { int ko_ = (t) << 6; \
    GLOAD16(sA0 + ko_, &lds[bi][dA0]); \
    GLOAD16(sA1 + ko_, &lds[bi][dA1]); \
    GLOAD16(sB0 + ko_, &lds[bi][dB0]); \
    GLOAD16(sB1 + ko_, &lds[bi][dB1]); }

    STAGE2(0, 0);
    STAGE2(1, 1);

    int cur = 0;
    for (int t = 0; t < nt; t++) {
        if (t == nt - 1) {
            asm volatile("s_waitcnt vmcnt(0)" ::: "memory");
        } else {
            asm volatile("s_waitcnt vmcnt(4)" ::: "memory");
        }
        __builtin_amdgcn_s_barrier();
        if (t + 2 < nt) {
            int tgt = cur - 1; if (tgt < 0) tgt += 3;
            STAGE2(t + 2, tgt);
        }
        const u16* L = &lds[cur][0];
        bf16x8 a0 = *(const bf16x8*)(L + oa00);
        bf16x8 a1 = *(const bf16x8*)(L + oa10);
        bf16x8 b0 = *(const bf16x8*)(L + ob00);
        bf16x8 b1 = *(const bf16x8*)(L + ob10);
        acc00 = __builtin_amdgcn_mfma_f32_16x16x32_bf16(a0, b0, acc00, 0, 0, 0);
        acc01 = __builtin_amdgcn_mfma_f32_16x16x32_bf16(a0, b1, acc01, 0, 0, 0);
        acc10 = __builtin_amdgcn_mfma_f32_16x16x32_bf16(a1, b0, acc10, 0, 0, 0);
        acc11 = __builtin_amdgcn_mfma_f32_16x16x32_bf16(a1, b1, acc11, 0, 0, 0);
        a0 = *(const bf16x8*)(L + oa01);
        a1 = *(const bf16x8*)(L + oa11);
        b0 = *(const bf16x8*)(L + ob01);
        b1 = *(const bf16x8*)(L + ob11);
        acc00 = __builtin_amdgcn_mfma_f32_16x16x32_bf16(a0, b0, acc00, 0, 0, 0);
        acc01 = __builtin_amdgcn_mfma_f32_16x16x32_bf16(a0, b1, acc01, 0, 0, 0);
        acc10 = __builtin_amdgcn_mfma_f32_16x16x32_bf16(a1, b0, acc10, 0, 0, 0);
        acc11 = __builtin_amdgcn_mfma_f32_16x16x32_bf16(a1, b1, acc11, 0, 0, 0);
        cur++; if (cur == 3) cur = 0;
    }
#undef STAGE2

    if (vtout && nBase >= 1024) {
        u16* T = &lds[0][0];
        __syncthreads();
        #pragma unroll
        for (int i = 0; i < 2; i++) {
            #pragma unroll
            for (int j = 0; j < 2; j++) {
                f32x4 v = (i == 0) ? (j == 0 ? acc00 : acc01) : (j == 0 ? acc10 : acc11);
                int dl = wc * 32 + j * 16 + r16;
                float bv = bias ? bias[nBase + dl] : 0.f;
                #pragma unroll
                for (int r = 0; r < 4; r++) {
                    int ml = wr * 32 + i * 16 + kg * 4 + r;
                    T[ml * 64 + dl] = f2bf(v[r] * alpha + bv);
                }
            }
        }
        __syncthreads();
        int d = tid & 63, cbv = (tid >> 6) & 1, half = tid >> 7;
        int hh = (nBase - 1024) >> 6;
        long long orow = ((long long)(cbv * 8 + hh) * 64 + d) * 1024 + (mBase >> 1) + half * 16;
        bf16x8 v0, v1;
        #pragma unroll
        for (int k = 0; k < 8; k++) {
            v0[k] = (short)T[((half * 16 + k) * 2 + cbv) * 64 + d];
            v1[k] = (short)T[((half * 16 + 8 + k) * 2 + cbv) * 64 + d];
        }
        *(bf16x8*)(vtout + orow) = v0;
        *(bf16x8*)(vtout + orow + 8) = v1;
        return;
    }

    #pragma unroll
    for (int i = 0; i < 2; i++) {
        #pragma unroll
        for (int j = 0; j < 2; j++) {
            f32x4 v = (i == 0) ? (j == 0 ? acc00 : acc01) : (j == 0 ? acc10 : acc11);
            int col = nBase + wc * 32 + j * 16 + r16;
            float bv = bias ? bias[col] : 0.f;
            long long base = offC + (long long)(mBase + wr * 32 + i * 16 + kg * 4) * ldc + col;
            #pragma unroll
            for (int r = 0; r < 4; r++) {
                float c = v[r] * alpha + bv;
                if (act == 2) {
                    float u = 0.7978845608028654f * (c + 0.044715f * c * c * c);
                    c = 0.5f * c * (1.f + tanhf(u));
                }
                if (cbf) ((u16*)Cv)[base + (long long)r * ldc] = f2bf(c);
                else     ((float*)Cv)[base + (long long)r * ldc] = c;
            }
        }
    }
}

// ---------------------------------------------------------------------------
// Flash v4 (R12): defer-max, kv-split x4, 1024 threads.
// ---------------------------------------------------------------------------
__global__ __launch_bounds__(1024) void flash_attn(
    const u16* __restrict__ qkvb, const u16* __restrict__ vtm,
    u16* __restrict__ attnb)
{
    int qt = blockIdx.x;
    int bh = blockIdx.y;
    int cb = bh >> 3, hh = bh & 7;
    int tid = threadIdx.x;
    int w = tid >> 6, lane = tid & 63;
    int p = w & 3, qf = w >> 2;
    int r16 = lane & 15, kg = lane >> 4;

    __shared__ __align__(16) u16 plds[16][2048];
    u16* pl = &plds[w][0];

    int qrow = qt * 64 + p * 16 + r16;
    const u16* qp = qkvb + ((long long)qrow * 2 + cb) * 1536 + hh * 64 + kg * 8;
    bf16x8 qf0 = scale8(*(const bf16x8*)(qp), 0.125f);
    bf16x8 qf1 = scale8(*(const bf16x8*)(qp + 32), 0.125f);

    const u16* kbase = qkvb + (long long)cb * 1536 + 512 + hh * 64;
    const u16* vbase = vtm + ((long long)bh * 64) * 1024;

    f32x4 l = {0.f, 0.f, 0.f, 0.f};
    f32x4 o[4] = {};

    int rb0 = (((r16 * 64 + kg * 8) * 2) ^ ((r16 & 7) << 4)) >> 1;
    int rb1 = (((r16 * 64 + 32 + kg * 8) * 2) ^ ((r16 & 7) << 4)) >> 1;

    for (int kt = qf * 4; kt < qf * 4 + 4; kt++) {
        f32x4 s[4];
        #pragma unroll
        for (int nb = 0; nb < 4; nb++) {
            int key = kt * 64 + nb * 16 + r16;
            const u16* kp = kbase + (long long)key * 3072 + kg * 8;
            bf16x8 kf0 = *(const bf16x8*)(kp);
            bf16x8 kf1 = *(const bf16x8*)(kp + 32);
            f32x4 acc = {};
            acc = __builtin_amdgcn_mfma_f32_16x16x32_bf16(qf0, kf0, acc, 0, 0, 0);
            acc = __builtin_amdgcn_mfma_f32_16x16x32_bf16(qf1, kf1, acc, 0, 0, 0);
            s[nb] = acc;
        }
        f32x4 rs = {};
        #pragma unroll
        for (int nb = 0; nb < 4; nb++)
            #pragma unroll
            for (int r = 0; r < 4; r++) {
                float pv = __expf(s[nb][r]);
                s[nb][r] = pv;
                rs[r] += pv;
            }
        #pragma unroll
        for (int off = 1; off < 16; off <<= 1) {
            #pragma unroll
            for (int r = 0; r < 4; r++) rs[r] += __shfl_xor(rs[r], off);
        }
        #pragma unroll
        for (int r = 0; r < 4; r++) l[r] += rs[r];

        #pragma unroll
        for (int nb = 0; nb < 4; nb++)
            #pragma unroll
            for (int r = 0; r < 4; r++) {
                int row = kg * 4 + r;
                int col = nb * 16 + r16;
                int byi = (((row * 64 + col) * 2) ^ ((row & 7) << 4)) >> 1;
                pl[byi] = f2bf(s[nb][r]);
            }

        bf16x8 pa0 = *(const bf16x8*)(pl + rb0);
        bf16x8 pa1 = *(const bf16x8*)(pl + rb1);
        #pragma unroll
        for (int db = 0; db < 4; db++) {
            const u16* vp = vbase + (long long)(db * 16 + r16) * 1024 + kt * 64 + kg * 8;
            bf16x8 vf0 = *(const bf16x8*)(vp);
            bf16x8 vf1 = *(const bf16x8*)(vp + 32);
            o[db] = __builtin_amdgcn_mfma_f32_16x16x32_bf16(pa0, vf0, o[db], 0, 0, 0);
            o[db] = __builtin_amdgcn_mfma_f32_16x16x32_bf16(pa1, vf1, o[db], 0, 0, 0);
        }
    }

    __syncthreads();
    float* fb = (float*)&plds[0][0];
    if (qf < 3) {
        int base = ((qf * 4 + p) * 64 + lane) * 20;
        #pragma unroll
        for (int r = 0; r < 4; r++) fb[base + r] = l[r];
        #pragma unroll
        for (int db = 0; db < 4; db++)
            #pragma unroll
            for (int r = 0; r < 4; r++) fb[base + 4 + db * 4 + r] = o[db][r];
    }
    __syncthreads();
    if (qf == 3) {
        #pragma unroll
        for (int q2 = 0; q2 < 3; q2++) {
            int base = ((q2 * 4 + p) * 64 + lane) * 20;
            #pragma unroll
            for (int r = 0; r < 4; r++) l[r] += fb[base + r];
            #pragma unroll
            for (int db = 0; db < 4; db++)
                #pragma unroll
                for (int r = 0; r < 4; r++) o[db][r] += fb[base + 4 + db * 4 + r];
        }
        f32x4 linv;
        #pragma unroll
        for (int r = 0; r < 4; r++) linv[r] = 1.f / l[r];
        #pragma unroll
        for (int db = 0; db < 4; db++)
            #pragma unroll
            for (int r = 0; r < 4; r++) {
                float val = o[db][r] * linv[r];
                int row = qt * 64 + p * 16 + kg * 4 + r;
                attnb[((long long)row * 2 + cb) * 512 + hh * 64 + db * 16 + r16] = f2bf(val);
            }
    }
}

// merged f32->bf16 convert for the 4 transformer weight tensors
__global__ __launch_bounds__(256) void cvt_all(
    const float* __restrict__ s0, const float* __restrict__ s1,
    const float* __restrict__ s2, const float* __restrict__ s3,
    u16* __restrict__ d0, u16* __restrict__ d1,
    u16* __restrict__ d2, u16* __restrict__ d3)
{
    const int n0 = 3145728, n1 = 1048576, n2 = 2097152, n3 = 2097152;
    int i = blockIdx.x * 256 + threadIdx.x;
    int st = gridDim.x * 256;
    for (; i < n0 + n1 + n2 + n3; i += st) {
        if (i < n0) d0[i] = f2bf(s0[i]);
        else if (i < n0 + n1) d1[i - n0] = f2bf(s1[i - n0]);
        else if (i < n0 + n1 + n2) d2[i - n0 - n1] = f2bf(s2[i - n0 - n1]);
        else d3[i - n0 - n1 - n2] = f2bf(s3[i - n0 - n1 - n2]);
    }
}

// Encoder: 256 blocks x 256 threads, 8 tokens/block, 2 cols/thread.
__global__ __launch_bounds__(256) void encoder_kernel(
    const float* __restrict__ x, const float* __restrict__ y,
    const float* __restrict__ enc_w, const float* __restrict__ enc_b,
    const float* __restrict__ yenc_w, const float* __restrict__ yenc_b,
    float* __restrict__ h, u16* __restrict__ h_bf)
{
    int g = blockIdx.x;            // 256 blocks
    int tid = threadIdx.x;
    __shared__ float xs[8][FDIM];
    __shared__ float ys[8];
    for (int i = tid; i < 8 * FDIM; i += 256) {
        int tk = i / FDIM, f = i % FDIM;
        xs[tk][f] = nanfix(x[(long long)(g * 8 + tk) * FDIM + f]);
    }
    if (tid < 8) ys[tid] = y[g * 8 + tid];
    __syncthreads();
    #pragma unroll
    for (int half = 0; half < 2; half++) {
        int e = tid + half * 256;
        float base = enc_b[e] + yenc_b[e];
        float yw = yenc_w[e];
        const float* wr = enc_w + (long long)e * FDIM;
        float acc[8];
        #pragma unroll
        for (int j = 0; j < 8; j++) acc[j] = 0.f;
        for (int f = 0; f < FDIM; f++) {
            float wv = wr[f];
            #pragma unroll
            for (int j = 0; j < 8; j++) acc[j] = fmaf(xs[j][f], wv, acc[j]);
        }
        #pragma unroll
        for (int j = 0; j < 8; j++) {
            float v = base + ys[j] * yw + acc[j];
            long long t = g * 8 + j;
            h[t * EDIM + e] = v;
            h_bf[t * EDIM + e] = f2bf(v);
        }
    }
}

// out = LN(a + p0 + p1 + cbias)*g + be ; float2-vectorized. a may alias out.
__global__ __launch_bounds__(256) void add_ln3_kernel(
    const float* a, const float* __restrict__ p0, const float* __restrict__ p1,
    const float* __restrict__ cbias,
    const float* __restrict__ g, const float* __restrict__ be,
    float* out, u16* __restrict__ out_bf)
{
    int row = blockIdx.x;
    int tid = threadIdx.x;
    const float2* pa  = (const float2*)(a + (long long)row * EDIM);
    const float2* pr0 = (const float2*)(p0 + (long long)row * EDIM);
    const float2* pr1 = (const float2*)(p1 + (long long)row * EDIM);
    const float2* cb2 = (const float2*)cbias;
    float2 A = pa[tid], P0 = pr0[tid], P1 = pr1[tid], CB = cb2[tid];
    float v0 = A.x + P0.x + P1.x + CB.x;
    float v1 = A.y + P0.y + P1.y + CB.y;
    float s = v0 + v1, q = v0 * v0 + v1 * v1;
    #pragma unroll
    for (int off = 32; off; off >>= 1) {
        s += __shfl_xor(s, off);
        q += __shfl_xor(q, off);
    }
    __shared__ float ss[4], sq[4];
    int w = tid >> 6, lane = tid & 63;
    if (lane == 0) { ss[w] = s; sq[w] = q; }
    __syncthreads();
    s = ss[0] + ss[1] + ss[2] + ss[3];
    q = sq[0] + sq[1] + sq[2] + sq[3];
    float mean = s * (1.f / EDIM);
    float var = q * (1.f / EDIM) - mean * mean;
    float rstd = rsqrtf(var + 1e-5f);
    float2 G = ((const float2*)g)[tid];
    float2 BE = ((const float2*)be)[tid];
    float o0 = (v0 - mean) * rstd * G.x + BE.x;
    float o1 = (v1 - mean) * rstd * G.y + BE.y;
    float2 O; O.x = o0; O.y = o1;
    ((float2*)(out + (long long)row * EDIM))[tid] = O;
    ((unsigned*)(out_bf + (long long)row * EDIM))[tid] =
        (unsigned)f2bf(o0) | ((unsigned)f2bf(o1) << 16);
}

// two-stage coalesced mean-pool
__global__ __launch_bounds__(1024) void pool1_kernel(
    const float* __restrict__ h, float* __restrict__ part)
{
    int j = blockIdx.x;
    int idx = threadIdx.x;
    float s = 0.f;
    #pragma unroll 8
    for (int k = 0; k < 32; k++)
        s += h[(long long)(j * 32 + k) * 1024 + idx];
    part[j * 1024 + idx] = s;
}
__global__ __launch_bounds__(1024) void pool2_kernel(
    const float* __restrict__ part, float* __restrict__ pooled)
{
    int idx = threadIdx.x;
    float s = 0.f;
    #pragma unroll 8
    for (int j = 0; j < 32; j++) s += part[j * 1024 + idx];
    pooled[idx] = s * (1.f / 1024.f);
}

__global__ __launch_bounds__(256) void wavedot2_kernel(
    const float* __restrict__ v0, const float* __restrict__ v1,
    const float* __restrict__ W, const float* __restrict__ bias,
    float* __restrict__ out0, float* __restrict__ out1,
    int R, int K, int act)
{
    int gw = (blockIdx.x * 256 + threadIdx.x) >> 6;
    int lane = threadIdx.x & 63;
    int nw = (gridDim.x * 256) >> 6;
    const float4* x0 = (const float4*)v0;
    const float4* x1 = (const float4*)v1;
    for (int r = gw; r < R; r += nw) {
        const float4* w4 = (const float4*)(W + (long long)r * K);
        float a0 = 0.f, a1 = 0.f;
        for (int i = lane; i < (K >> 2); i += 64) {
            float4 w = w4[i];
            float4 p = x0[i];
            float4 q = x1[i];
            a0 += w.x * p.x + w.y * p.y + w.z * p.z + w.w * p.w;
            a1 += w.x * q.x + w.y * q.y + w.z * q.z + w.w * q.w;
        }
        #pragma unroll
        for (int off = 32; off; off >>= 1) {
            a0 += __shfl_xor(a0, off);
            a1 += __shfl_xor(a1, off);
        }
        if (lane == 0) {
            float bb = bias[r];
            float o0 = a0 + bb, o1 = a1 + bb;
            if (act == 1) { o0 = fmaxf(o0, 0.f); o1 = fmaxf(o1, 0.f); }
            out0[r] = o0; out1[r] = o1;
        }
    }
}

// Final per-sample MLP: 512 blocks x 128 threads, 4 same-parity tokens/block.
__global__ __launch_bounds__(128) void final_mlp_kernel(
    const float* __restrict__ x, const float* __restrict__ flat,
    float* __restrict__ out)
{
    int g = blockIdx.x;            // 512 blocks
    int b = g >> 8;
    int j0 = (g & 255) * 4;
    int tid = threadIdx.x;
    const float* fl = flat + (long long)b * TOTALW;
    __shared__ float xs[4][FDIM], t1s[4][HDIM], t2s[4][HDIM];
    for (int i = tid; i < 4 * FDIM; i += 128) {
        int j = i / FDIM, f = i % FDIM;
        int t = (j0 + j) * 2 + b;
        xs[j][f] = nanfix(x[(long long)(NTOK + t) * FDIM + f]);
    }
    __syncthreads();
    {
        float acc[4];
        float b1 = fl[tid];
        #pragma unroll
        for (int j = 0; j < 4; j++) acc[j] = b1;
        const float* w1 = fl + HDIM;
        for (int f = 0; f < FDIM; f++) {
            float wv = w1[f * HDIM + tid];
            #pragma unroll
            for (int j = 0; j < 4; j++) acc[j] = fmaf(xs[j][f], wv, acc[j]);
        }
        #pragma unroll
        for (int j = 0; j < 4; j++) t1s[j][tid] = fmaxf(acc[j], 0.f);
    }
    __syncthreads();
    {
        float acc[4];
        float b2 = fl[12928 + tid];
        #pragma unroll
        for (int j = 0; j < 4; j++) acc[j] = b2;
        const float* w2 = fl + 13056;
        for (int hh = 0; hh < HDIM; hh++) {
            float wv = w2[hh * HDIM + tid];
            #pragma unroll
            for (int j = 0; j < 4; j++) acc[j] = fmaf(t1s[j][hh], wv, acc[j]);
        }
        #pragma unroll
        for (int j = 0; j < 4; j++) t2s[j][tid] = fmaxf(acc[j], 0.f);
    }
    __syncthreads();
    if (tid < NOUTD) {
        float acc[4];
        float b3 = fl[29440 + tid];
        #pragma unroll
        for (int j = 0; j < 4; j++) acc[j] = b3;
        const float* w3 = fl + 29450;
        for (int hh = 0; hh < HDIM; hh++) {
            float wv = w3[hh * NOUTD + tid];
            #pragma unroll
            for (int j = 0; j < 4; j++) acc[j] = fmaf(t2s[j][hh], wv, acc[j]);
        }
        #pragma unroll
        for (int j = 0; j < 4; j++) {
            int t = (j0 + j) * 2 + b;
            out[(long long)t * NOUTD + tid] = acc[j];
        }
    }
}

// ---------------------------------------------------------------------------
extern "C" void kernel_launch(void* const* d_in, const int* in_sizes, int n_in,
                              void* d_out, int out_size, void* d_ws, size_t ws_size,
                              hipStream_t stream) {
    const float* x      = (const float*)d_in[0];
    const float* y      = (const float*)d_in[1];
    const float* enc_w  = (const float*)d_in[2];
    const float* enc_b  = (const float*)d_in[3];
    const float* yenc_w = (const float*)d_in[4];
    const float* yenc_b = (const float*)d_in[5];
    const float* qkv_w  = (const float*)d_in[6];
    const float* qkv_b  = (const float*)d_in[7];
    const float* out_w  = (const float*)d_in[8];
    const float* out_b  = (const float*)d_in[9];
    const float* ln1_g  = (const float*)d_in[10];
    const float* ln1_b  = (const float*)d_in[11];
    const float* ln2_g  = (const float*)d_in[12];
    const float* ln2_b  = (const float*)d_in[13];
    const float* ff1_w  = (const float*)d_in[14];
    const float* ff1_b  = (const float*)d_in[15];
    const float* ff2_w  = (const float*)d_in[16];
    const float* ff2_b  = (const float*)d_in[17];
    const float* dec_w1 = (const float*)d_in[18];
    const float* dec_b1 = (const float*)d_in[19];
    const float* dec_w2 = (const float*)d_in[20];
    const float* dec_b2 = (const float*)d_in[21];

    float* ws     = (float*)d_ws;
    float* h      = ws;
    u16*   h_bf   = (u16*)(h + 1048576);
    u16*   qkv_bf = h_bf + 1048576;
    u16*   vt     = qkv_bf + 3145728;
    u16*   attn_bf= vt + 1048576;
    u16*   ffb_bf = attn_bf + 1048576;
    u16*   wq     = ffb_bf + 2097152;
    u16*   wo     = wq + 3145728;
    u16*   wf1    = wo + 1048576;
    u16*   wf2    = wf1 + 2097152;
    float* big    = (float*)(wf2 + 2097152);
    float* big2   = big + 1048576;
    float* part   = big2 + 1048576;
    float* pooled = part + 32768;
    float* dbuf   = pooled + 1024;
    float* flat   = dbuf + 4096;

    cvt_all<<<4096, 256, 0, stream>>>(qkv_w, out_w, ff1_w, ff2_w, wq, wo, wf1, wf2);

    encoder_kernel<<<256, 256, 0, stream>>>(x, y, enc_w, enc_b, yenc_w, yenc_b, h, h_bf);

    const long long PSTRIDE = (long long)NTOK * EDIM;

    for (int l = 0; l < NLAYER; l++) {
        gemm2<<<dim3(24, 32, 1), 256, 0, stream>>>(
            h_bf, EDIM, wq + (size_t)l * 786432, EDIM,
            qkv_bf, 1536, 1, EDIM, 0, 1.f, qkv_b + (size_t)l * 1536, 0, vt);

        flash_attn<<<dim3(16, 16), 1024, 0, stream>>>(qkv_bf, vt, attn_bf);

        gemm2<<<dim3(8, 32, 2), 256, 0, stream>>>(
            attn_bf, EDIM, wo + (size_t)l * 262144, EDIM,
            big, EDIM, 0, 256, PSTRIDE, 1.f, nullptr, 0, nullptr);

        add_ln3_kernel<<<NTOK, 256, 0, stream>>>(h, big, big2,
            out_b + (size_t)l * EDIM,
            ln1_g + (size_t)l * EDIM, ln1_b + (size_t)l * EDIM, h, h_bf);

        gemm2<<<dim3(16, 32, 1), 256, 0, stream>>>(
            h_bf, EDIM, wf1 + (size_t)l * 524288, EDIM,
            ffb_bf, NHID, 1, EDIM, 0, 1.f, ff1_b + (size_t)l * NHID, 2, nullptr);

        gemm2<<<dim3(8, 32, 2), 256, 0, stream>>>(
            ffb_bf, NHID, wf2 + (size_t)l * 524288, NHID,
            big, EDIM, 0, 512, PSTRIDE, 1.f, nullptr, 0, nullptr);

        add_ln3_kernel<<<NTOK, 256, 0, stream>>>(h, big, big2,
            ff2_b + (size_t)l * EDIM,
            ln2_g + (size_t)l * EDIM, ln2_b + (size_t)l * EDIM, h, h_bf);
    }

    pool1_kernel<<<32, 1024, 0, stream>>>(h, part);
    pool2_kernel<<<1, 1024, 0, stream>>>(part, pooled);

    wavedot2_kernel<<<512, 256, 0, stream>>>(
        pooled, pooled + EDIM, dec_w1, dec_b1, dbuf, dbuf + DECD, DECD, EDIM, 1);

    wavedot2_kernel<<<7683, 256, 0, stream>>>(
        dbuf, dbuf + DECD, dec_w2, dec_b2, flat, flat + TOTALW, TOTALW, DECD, 0);

    final_mlp_kernel<<<512, 128, 0, stream>>>(x, flat, (float*)d_out);
}